// Round 1
// 1675.624 us; speedup vs baseline: 1.0401x; 1.0401x over previous
//
#include <hip/hip_runtime.h>
#include <hip/hip_bf16.h>
#include <cstdint>
#include <cstdio>

// ---------- problem constants ----------
#define M_TOK   200704      // 4096 windows * 49 tokens
#define DIM     512
#define QKV_N   1536
#define NWIN    4096
#define NTOK    49
#define NHEAD   16
#define HD      32
#define TABLE_N 169

typedef float  f32x4  __attribute__((ext_vector_type(4)));
typedef __bf16 bf16x8 __attribute__((ext_vector_type(8)));

__device__ __forceinline__ unsigned short f2bf(float f) {
  union { float f; unsigned u; } v; v.f = f;
  unsigned r = (v.u + 0x7FFFu + ((v.u >> 16) & 1u)) >> 16;
  return (unsigned short)r;
}

// async global->LDS, 16B per lane; LDS dest is wave-uniform base + lane*16
__device__ __forceinline__ void gload_lds16(const void* gsrc, void* ldst) {
  __builtin_amdgcn_global_load_lds(
      (const __attribute__((address_space(1))) void*)gsrc,
      (__attribute__((address_space(3))) void*)ldst,
      16, 0, 0);
}

// ---------- cast: x f32 -> bf16 (8 elems/thread) ----------
__global__ __launch_bounds__(256) void cast_kernel(
    const float* __restrict__ x, unsigned short* __restrict__ xb)
{
  size_t i = ((size_t)blockIdx.x * 256 + threadIdx.x) * 8;
  float4 a = *(const float4*)(x + i);
  float4 b = *(const float4*)(x + i + 4);
  union { unsigned short s[8]; uint4 v; } pk;
  pk.s[0] = f2bf(a.x); pk.s[1] = f2bf(a.y);
  pk.s[2] = f2bf(a.z); pk.s[3] = f2bf(a.w);
  pk.s[4] = f2bf(b.x); pk.s[5] = f2bf(b.y);
  pk.s[6] = f2bf(b.z); pk.s[7] = f2bf(b.w);
  *(uint4*)(xb + i) = pk.v;
}

// ---------- prep: transpose+cast weights, materialize bias table ----------
__global__ __launch_bounds__(256) void prep_kernel(
    const float* __restrict__ qkv_w, const float* __restrict__ proj_w,
    const float* __restrict__ table, const int* __restrict__ rel_idx,
    unsigned short* __restrict__ Wt, unsigned short* __restrict__ Pt,
    float* __restrict__ biasFull)
{
  int i = blockIdx.x * 256 + threadIdx.x;
  if (i < 786432) {                       // 1536*512
    int n = i >> 9, k = i & 511;
    Wt[i] = f2bf(qkv_w[(size_t)k * 1536 + n]);
  } else if (i < 786432 + 262144) {       // 512*512
    int j = i - 786432;
    int n = j >> 9, k = j & 511;
    Pt[j] = f2bf(proj_w[(size_t)k * 512 + n]);
  } else if (i < 786432 + 262144 + NHEAD * NTOK * NTOK) {
    int j = i - 1048576;
    int h = j / (NTOK * NTOK), r = j % (NTOK * NTOK);
    biasFull[j] = table[(size_t)rel_idx[r] * NHEAD + h];
  }
}

// ---------- GEMM: C[M,N] = A[M,K] @ Bt[N,K]^T + bias[N] ----------
// m97 structure: 128x128 tile, BK=32, 256 threads = 4 waves (2x2), 64x64/wave,
// global_load_lds width-16 staging into linear LDS, mfma_f32_16x16x32_bf16.
// A is always bf16. XCD-chunked bijective block swizzle (nwg % 8 == 0).
template<bool CF32>
__global__ __launch_bounds__(256) void gemm_bt(
    const unsigned short* __restrict__ A, const unsigned short* __restrict__ Bt,
    const float* __restrict__ bias, void* __restrict__ Cp,
    int M, int N, int K)
{
  __shared__ unsigned short As[128 * 32];
  __shared__ unsigned short Bs[128 * 32];
  const int tid  = threadIdx.x;
  const int lane = tid & 63;
  const int wave = tid >> 6;
  const int quad = lane >> 4, l16 = lane & 15;
  const int wm = (wave >> 1) * 64, wn = (wave & 1) * 64;

  // XCD-aware swizzle: each XCD owns a contiguous chunk of the flat grid.
  // nwg = 12*1568 = 18816 and 4*1568 = 6272 -- both divisible by 8.
  const unsigned nwg  = gridDim.x * gridDim.y;
  const unsigned flat = blockIdx.y * gridDim.x + blockIdx.x;
  const unsigned cpx  = nwg >> 3;
  const unsigned swz  = (flat & 7u) * cpx + (flat >> 3);
  const size_t n0 = (size_t)(swz % gridDim.x) * 128;
  const size_t m0 = (size_t)(swz / gridDim.x) * 128;

  f32x4 acc[4][4] = {};

  for (int kb = 0; kb < K; kb += 32) {
    // ---- stage A,B (128 rows x 32 k each, bf16): 2 x 16B-chunks/thread ----
    // chunk c -> row = c>>2, col = (c&3)*8 shorts; LDS linear = chunk order.
    #pragma unroll
    for (int p = 0; p < 2; ++p) {
      int c = p * 256 + tid;
      int r = c >> 2, c8 = (c & 3) * 8;
      gload_lds16(A  + (m0 + r) * (size_t)K + kb + c8,
                  &As[(p * 256 + wave * 64) * 8]);
      gload_lds16(Bt + (n0 + r) * (size_t)K + kb + c8,
                  &Bs[(p * 256 + wave * 64) * 8]);
    }
    __syncthreads();

    bf16x8 afr[4], bfr[4];
    #pragma unroll
    for (int mt = 0; mt < 4; ++mt)
      afr[mt] = *(const bf16x8*)(&As[(wm + mt * 16 + l16) * 32 + quad * 8]);
    #pragma unroll
    for (int nt = 0; nt < 4; ++nt)
      bfr[nt] = *(const bf16x8*)(&Bs[(wn + nt * 16 + l16) * 32 + quad * 8]);
    #pragma unroll
    for (int mt = 0; mt < 4; ++mt)
      #pragma unroll
      for (int nt = 0; nt < 4; ++nt)
        acc[mt][nt] = __builtin_amdgcn_mfma_f32_16x16x32_bf16(
            afr[mt], bfr[nt], acc[mt][nt], 0, 0, 0);
    __syncthreads();
  }

  // ---- epilogue: + bias, store (C/D layout: col=l16, row=quad*4+reg) ----
  float bcol[4];
  #pragma unroll
  for (int nt = 0; nt < 4; ++nt) bcol[nt] = bias[n0 + wn + nt * 16 + l16];
  float*          Cf = (float*)Cp;
  unsigned short* Ch = (unsigned short*)Cp;
  #pragma unroll
  for (int mt = 0; mt < 4; ++mt)
    #pragma unroll
    for (int r = 0; r < 4; ++r) {
      size_t row = m0 + wm + mt * 16 + quad * 4 + r;
      #pragma unroll
      for (int nt = 0; nt < 4; ++nt) {
        size_t col = n0 + wn + nt * 16 + l16;
        float v = acc[mt][nt][r] + bcol[nt];
        if (CF32) Cf[row * (size_t)N + col] = v;
        else      Ch[row * (size_t)N + col] = f2bf(v);
      }
    }
}

// ---------- attention: 1 wave per (window, head) ----------
__global__ __launch_bounds__(256) void attn_kernel(
    const unsigned short* __restrict__ qkv,
    const float* __restrict__ biasFull,
    unsigned short* __restrict__ attn_out)
{
  const int b    = blockIdx.x >> 2;
  const int qh   = blockIdx.x & 3;
  const int wave = threadIdx.x >> 6;
  const int h    = qh * 4 + wave;
  const int lane = threadIdx.x & 63;
  const int quad = lane >> 4, l16 = lane & 15;

  __shared__ unsigned short smem[4 * 6144];
  unsigned short* wbase = smem + wave * 6144;
  unsigned short* Qs = wbase;
  unsigned short* Ks = wbase + 2048;
  unsigned short* Vt = wbase + 4096;
  unsigned short* Ps = wbase;          // aliases Qs+Ks after QK^T

  const size_t rowb = (size_t)b * NTOK;

  #pragma unroll
  for (int seg = 0; seg < 4; ++seg) {
    int t  = seg * 16 + (lane >> 2);
    int c8 = (lane & 3) * 8;
    uint4 zq = {0, 0, 0, 0}, zk = {0, 0, 0, 0}, zv = {0, 0, 0, 0};
    if (t < NTOK) {
      const unsigned short* g = qkv + (rowb + t) * 1536 + h * 32 + c8;
      zq = *(const uint4*)(g);
      zk = *(const uint4*)(g + 512);
      zv = *(const uint4*)(g + 1024);
    }
    *(uint4*)(Qs + t * 32 + c8) = zq;
    *(uint4*)(Ks + t * 32 + c8) = zk;
    union { uint4 v; unsigned short s[8]; } uv; uv.v = zv;
    #pragma unroll
    for (int j = 0; j < 8; ++j) Vt[(c8 + j) * 64 + t] = uv.s[j];
  }

  f32x4 sacc[4][4] = {};
  {
    bf16x8 aq[4], ak[4];
    #pragma unroll
    for (int mt = 0; mt < 4; ++mt)
      aq[mt] = *(const bf16x8*)(Qs + (mt * 16 + l16) * 32 + quad * 8);
    #pragma unroll
    for (int nt = 0; nt < 4; ++nt)
      ak[nt] = *(const bf16x8*)(Ks + (nt * 16 + l16) * 32 + quad * 8);
    #pragma unroll
    for (int mt = 0; mt < 4; ++mt)
      #pragma unroll
      for (int nt = 0; nt < 4; ++nt)
        sacc[mt][nt] = __builtin_amdgcn_mfma_f32_16x16x32_bf16(
            aq[mt], ak[nt], sacc[mt][nt], 0, 0, 0);
  }

  const float scale = 0.17677669529663687f;   // 1/sqrt(32)
  const float* bh = biasFull + h * (NTOK * NTOK);
  #pragma unroll
  for (int mt = 0; mt < 4; ++mt) {
    #pragma unroll
    for (int r = 0; r < 4; ++r) {
      int m = mt * 16 + quad * 4 + r;
      float v[4];
      #pragma unroll
      for (int nt = 0; nt < 4; ++nt) {
        int n = nt * 16 + l16;
        float s = sacc[mt][nt][r] * scale;
        if (m < NTOK && n < NTOK) s += bh[m * NTOK + n];
        v[nt] = (n < NTOK) ? s : -1e30f;
      }
      float mx = fmaxf(fmaxf(v[0], v[1]), fmaxf(v[2], v[3]));
      #pragma unroll
      for (int off = 1; off <= 8; off <<= 1) mx = fmaxf(mx, __shfl_xor(mx, off, 64));
      float e[4], sum = 0.f;
      #pragma unroll
      for (int nt = 0; nt < 4; ++nt) { e[nt] = __expf(v[nt] - mx); sum += e[nt]; }
      #pragma unroll
      for (int off = 1; off <= 8; off <<= 1) sum += __shfl_xor(sum, off, 64);
      float inv = 1.0f / sum;
      #pragma unroll
      for (int nt = 0; nt < 4; ++nt)
        Ps[m * 64 + nt * 16 + l16] = f2bf(e[nt] * inv);
    }
  }

  f32x4 oacc[4][2] = {};
  #pragma unroll
  for (int kt = 0; kt < 2; ++kt) {
    bf16x8 ap[4], av[2];
    #pragma unroll
    for (int mt = 0; mt < 4; ++mt)
      ap[mt] = *(const bf16x8*)(Ps + (mt * 16 + l16) * 64 + kt * 32 + quad * 8);
    #pragma unroll
    for (int dt = 0; dt < 2; ++dt)
      av[dt] = *(const bf16x8*)(Vt + (dt * 16 + l16) * 64 + kt * 32 + quad * 8);
    #pragma unroll
    for (int mt = 0; mt < 4; ++mt)
      #pragma unroll
      for (int dt = 0; dt < 2; ++dt)
        oacc[mt][dt] = __builtin_amdgcn_mfma_f32_16x16x32_bf16(
            ap[mt], av[dt], oacc[mt][dt], 0, 0, 0);
  }

  #pragma unroll
  for (int mt = 0; mt < 4; ++mt)
    #pragma unroll
    for (int r = 0; r < 4; ++r) {
      int m = mt * 16 + quad * 4 + r;
      if (m < NTOK) {
        #pragma unroll
        for (int dt = 0; dt < 2; ++dt)
          attn_out[(rowb + m) * 512 + h * 32 + dt * 16 + l16] =
              f2bf(oacc[mt][dt][r]);
      }
    }
}

// ---------- workspace layout ----------
// xb (bf16 cast of x) ALIASES the attn_out region: xb is only live from
// cast_kernel through gemm1; attn_out is first written by attn_kernel (later).
#define WS_QKV   0ull
#define WS_ATTN  616562688ull          // 200704*1536*2
#define WS_WT    822083584ull          // + 200704*512*2
#define WS_PT    823656448ull          // + 1536*512*2
#define WS_BIAS  824180736ull          // + 512*512*2
#define WS_END   824334400ull          // + 16*49*49*4

extern "C" void kernel_launch(void* const* d_in, const int* in_sizes, int n_in,
                              void* d_out, int out_size, void* d_ws, size_t ws_size,
                              hipStream_t stream) {
  const float* x       = (const float*)d_in[0];
  const float* qkv_w   = (const float*)d_in[1];
  const float* qkv_b   = (const float*)d_in[2];
  const float* proj_w  = (const float*)d_in[3];
  const float* proj_b  = (const float*)d_in[4];
  const float* table   = (const float*)d_in[5];
  const int*   rel_idx = (const int*)d_in[6];
  float* out = (float*)d_out;

  if (ws_size < WS_END) {
    fprintf(stderr, "kernel_launch: ws_size %zu < needed %llu\n", ws_size, WS_END);
    return;
  }
  char* ws = (char*)d_ws;
  unsigned short* qkv   = (unsigned short*)(ws + WS_QKV);
  unsigned short* attnb = (unsigned short*)(ws + WS_ATTN);
  unsigned short* xb    = (unsigned short*)(ws + WS_ATTN);  // alias (see above)
  unsigned short* Wt    = (unsigned short*)(ws + WS_WT);
  unsigned short* Pt    = (unsigned short*)(ws + WS_PT);
  float*          biasF = (float*)(ws + WS_BIAS);

  // 1) x -> bf16 (102760448 elems / 8 per thread / 256 per block = 50176)
  cast_kernel<<<50176, 256, 0, stream>>>(x, xb);

  // 1b) prep: weight transpose+cast, bias gather
  prep_kernel<<<4247, 256, 0, stream>>>(qkv_w, proj_w, table, rel_idx, Wt, Pt, biasF);

  // 2) qkv = x @ qkv_w + qkv_b  -> bf16
  dim3 g1(QKV_N / 128, M_TOK / 128);
  gemm_bt<false><<<g1, 256, 0, stream>>>(xb, Wt, qkv_b, qkv, M_TOK, QKV_N, DIM);

  // 3) window attention
  attn_kernel<<<NWIN * 4, 256, 0, stream>>>(qkv, biasF, attnb);

  // 4) out = attn @ proj_w + proj_b -> fp32
  dim3 g2(DIM / 128, M_TOK / 128);
  gemm_bt<true><<<g2, 256, 0, stream>>>(attnb, Pt, proj_b, out, M_TOK, DIM, DIM);
}